// Round 5
// baseline (837.846 us; speedup 1.0000x reference)
//
#include <hip/hip_runtime.h>
#include <hip/hip_bf16.h>
#include <math.h>

#define Mrows 4096      // B*T
#define Kdim  256       // F
#define Ncols 16384     // G*V
#define Vsz   8192
#define NSEG  32        // marg_acc row segments (128 rows each)

typedef __attribute__((ext_vector_type(8))) short bf16x8;
typedef __attribute__((ext_vector_type(4))) float f32x4;

// async global->LDS, 16 bytes per lane (dest must be linear: base + lane*16)
#define GLD16(ldsp, gp) __builtin_amdgcn_global_load_lds(                          \
    (const __attribute__((address_space(1))) unsigned int*)(gp),                   \
    (__attribute__((address_space(3))) unsigned int*)(ldsp), 16, 0, 0)

// ---------------- split fp32 -> bf16 (hi, lo) ---------------------------------
__global__ __launch_bounds__(256) void split_bf16(const float* __restrict__ src,
                                                  __hip_bfloat16* __restrict__ hi,
                                                  __hip_bfloat16* __restrict__ lo) {
    const int i = blockIdx.x * 256 + threadIdx.x;
    const float v = src[i];
    const __hip_bfloat16 h = __float2bfloat16(v);
    const float hf = __bfloat162float(h);
    hi[i] = h;
    lo[i] = __float2bfloat16(v - hf);
}

// ---------------- GEMM: ehid[m][n] = exp(sum_k A[m][k]*B[n][k] + bias[n]) -----
// split-bf16 3-term MFMA, 128x128 tile, BK=32, global_load_lds staging.
// Epilogue stores exp(h): phase2/marg_acc then never need a transcendental
// for the softmax numerators (h in ~[-3,3] so exp never overflows).
__global__ __launch_bounds__(256, 3) void gemm_mfma(const __hip_bfloat16* __restrict__ Ahi,
                                                    const __hip_bfloat16* __restrict__ Alo,
                                                    const __hip_bfloat16* __restrict__ Bhi,
                                                    const __hip_bfloat16* __restrict__ Blo,
                                                    const float* __restrict__ bias,
                                                    float* __restrict__ ehid) {
    __shared__ unsigned short Ah[128 * 32], Al[128 * 32], Bh[128 * 32], Bl[128 * 32];
    const int tid = threadIdx.x;
    const int lane = tid & 63;
    const int wave = tid >> 6;

    // bijective XCD tile swizzle: nwg = gx*gy is always a multiple of 8 here
    const int gx = gridDim.x;
    int fid = blockIdx.y * gx + blockIdx.x;
    const int per = (gx * gridDim.y) >> 3;
    fid = (fid & 7) * per + (fid >> 3);
    const int bm = (fid % gx) * 128;            // m tile
    const int bn = (fid / gx) * 128;            // n tile

    const int wm = (wave & 1) * 64;
    const int wn = (wave >> 1) * 64;
    const int lm = lane & 15;                   // row within 16
    const int sl = (((lane >> 4) ^ (lm & 3)) << 3);   // swizzled k-octet (shorts)

    f32x4 acc[4][4];
#pragma unroll
    for (int i = 0; i < 4; ++i)
#pragma unroll
        for (int j = 0; j < 4; ++j) acc[i][j] = (f32x4){0.f, 0.f, 0.f, 0.f};

    for (int k0 = 0; k0 < Kdim; k0 += 32) {
        __syncthreads();
#pragma unroll
        for (int t = 0; t < 2; ++t) {
            const int c = tid + t * 256;        // 0..511; LDS dest byte = c*16 (linear)
            const int row = c >> 2;             // 0..127
            const int ko = (((c & 3) ^ (row & 3)) << 3);   // pre-swizzled source octet
            const size_t ga = (size_t)(bm + row) * Kdim + k0 + ko;
            const size_t gb = (size_t)(bn + row) * Kdim + k0 + ko;
            GLD16(&Ah[c * 8], Ahi + ga);
            GLD16(&Al[c * 8], Alo + ga);
            GLD16(&Bh[c * 8], Bhi + gb);
            GLD16(&Bl[c * 8], Blo + gb);
        }
        __syncthreads();                        // drains vmcnt (staging complete)

        bf16x8 ah[4], al[4], bh[4], bl[4];
#pragma unroll
        for (int i = 0; i < 4; ++i) {
            ah[i] = *(const bf16x8*)&Ah[(wm + i * 16 + lm) * 32 + sl];
            al[i] = *(const bf16x8*)&Al[(wm + i * 16 + lm) * 32 + sl];
            bh[i] = *(const bf16x8*)&Bh[(wn + i * 16 + lm) * 32 + sl];
            bl[i] = *(const bf16x8*)&Bl[(wn + i * 16 + lm) * 32 + sl];
        }
        // term-major: 16 independent MFMAs per term; acc reuse distance = 16
#pragma unroll
        for (int j = 0; j < 4; ++j)
#pragma unroll
            for (int i = 0; i < 4; ++i)
                acc[i][j] = __builtin_amdgcn_mfma_f32_16x16x32_bf16(ah[i], bh[j], acc[i][j], 0, 0, 0);
#pragma unroll
        for (int j = 0; j < 4; ++j)
#pragma unroll
            for (int i = 0; i < 4; ++i)
                acc[i][j] = __builtin_amdgcn_mfma_f32_16x16x32_bf16(ah[i], bl[j], acc[i][j], 0, 0, 0);
#pragma unroll
        for (int j = 0; j < 4; ++j)
#pragma unroll
            for (int i = 0; i < 4; ++i)
                acc[i][j] = __builtin_amdgcn_mfma_f32_16x16x32_bf16(al[i], bh[j], acc[i][j], 0, 0, 0);
    }

    // epilogue: C/D layout col=lane&15, row=(lane>>4)*4+reg  [m89/m91 verified]
    const int rbase = (lane >> 4) * 4;
#pragma unroll
    for (int j = 0; j < 4; ++j) {
        const int n = bn + wn + j * 16 + lm;
        const float bj = bias[n];
#pragma unroll
        for (int i = 0; i < 4; ++i) {
            const int m0 = bm + wm + i * 16 + rbase;
#pragma unroll
            for (int r2 = 0; r2 < 4; ++r2)
                ehid[(size_t)(m0 + r2) * Ncols + n] = __expf(acc[i][j][r2] + bj);
        }
    }
}

// gumbel ratio in exp domain: ratio = eh / (-log(u)); poly for u>0.8 (hw log
// abs-error zone near u->1), native log otherwise. rcp: 1-ulp v_rcp_f32.
#define GUMRATIO(EH, UU, ROUT) {                                                   \
    float uu = fminf(fmaxf((UU), 1.17549435e-38f), 1.0f);                          \
    const float d = uu - 1.0f;                                                     \
    float q = 1.0f / 9.0f;                                                         \
    q = fmaf(q, d, -0.125f);                                                       \
    q = fmaf(q, d, 1.0f / 7.0f);                                                   \
    q = fmaf(q, d, -1.0f / 6.0f);                                                  \
    q = fmaf(q, d, 0.2f);                                                          \
    q = fmaf(q, d, -0.25f);                                                        \
    q = fmaf(q, d, 1.0f / 3.0f);                                                   \
    q = fmaf(q, d, -0.5f);                                                         \
    q = fmaf(q, d, 1.0f);                                                          \
    const float inner = (d > -0.2f) ? (-d) * q : -__logf(uu);                      \
    ROUT = (EH) * __builtin_amdgcn_rcpf(inner); }

// ---------------- Phase 2: exp-domain softmax, argmax, codevectors ------------
// One WAVE owns TWO rows (same g): emb gather (32 B/elem) amortized across both.
// No transcendental except the partial log path; no max-tracking/rescale:
// p = ratio/S1 with ratio = eh*rcp(-log u). Writes per row: codevectors,
// argmax, mask*(1/S2) for the marginal kernel (S2 = sum eh).
__global__ __launch_bounds__(256, 4) void phase2(const float* __restrict__ ehid,
                                                 const float* __restrict__ u,
                                                 const float* __restrict__ emb,
                                                 const int* __restrict__ mask,
                                                 float* __restrict__ mrow,
                                                 float* __restrict__ out) {
    const int tid = threadIdx.x;
    const int lane = tid & 63;
    const int wid = tid >> 6;
    const int n = blockIdx.x * 8 + wid * 2;     // rows n, n+1
    const int g = blockIdx.y;

    const float* ha = ehid + (size_t)n * Ncols + (size_t)g * Vsz;
    const float* hb = ha + Ncols;
    const float* ua = u + ((size_t)n * 2 + g) * Vsz;
    const float* ub = ua + 2 * Vsz;
    const float* embg = emb + (size_t)g * Vsz * 8;
    const int mka = mask[n], mkb = mask[n + 1];

    float s1a = 0.f, s2a = 0.f, s1b = 0.f, s2b = 0.f;
    float bra = -1.f, brb = -1.f;
    int bia = 0, bib = 0;
    float cva[8], cvb[8];
#pragma unroll
    for (int d2 = 0; d2 < 8; ++d2) { cva[d2] = 0.f; cvb[d2] = 0.f; }

    float HA0[4], UA0[4], HB0[4], UB0[4], HA1[4], UA1[4], HB1[4], UB1[4];
#pragma unroll
    for (int k = 0; k < 4; ++k) {
        const int v = k * 64 + lane;
        HA0[k] = ha[v]; UA0[k] = __builtin_nontemporal_load(ua + v);
        HB0[k] = hb[v]; UB0[k] = __builtin_nontemporal_load(ub + v);
    }

#define CHUNK(CHA, CUA, CHB, CUB, NHA, NUA, NHB, NUB, c) {                         \
    if ((c) + 1 < 32) {   /* prefetch next chunk */                                \
        const int vb = ((c) + 1) * 256 + lane;                                     \
        _Pragma("unroll")                                                          \
        for (int k = 0; k < 4; ++k) {                                              \
            NHA[k] = ha[vb + k * 64];                                              \
            NUA[k] = __builtin_nontemporal_load(ua + vb + k * 64);                 \
            NHB[k] = hb[vb + k * 64];                                              \
            NUB[k] = __builtin_nontemporal_load(ub + vb + k * 64);                 \
        }                                                                          \
    }                                                                              \
    _Pragma("unroll")                                                              \
    for (int k = 0; k < 4; ++k) {                                                  \
        const int v = (c) * 256 + k * 64 + lane;                                   \
        float ra, rb;                                                              \
        GUMRATIO(CHA[k], CUA[k], ra)                                               \
        GUMRATIO(CHB[k], CUB[k], rb)                                               \
        s1a += ra; s2a += CHA[k];                                                  \
        s1b += rb; s2b += CHB[k];                                                  \
        if (ra > bra) { bra = ra; bia = v; }                                       \
        if (rb > brb) { brb = rb; bib = v; }                                       \
        const float4 e0 = *(const float4*)(embg + (size_t)v * 8);                  \
        const float4 e1 = *(const float4*)(embg + (size_t)v * 8 + 4);              \
        cva[0] = fmaf(ra, e0.x, cva[0]); cva[1] = fmaf(ra, e0.y, cva[1]);          \
        cva[2] = fmaf(ra, e0.z, cva[2]); cva[3] = fmaf(ra, e0.w, cva[3]);          \
        cva[4] = fmaf(ra, e1.x, cva[4]); cva[5] = fmaf(ra, e1.y, cva[5]);          \
        cva[6] = fmaf(ra, e1.z, cva[6]); cva[7] = fmaf(ra, e1.w, cva[7]);          \
        cvb[0] = fmaf(rb, e0.x, cvb[0]); cvb[1] = fmaf(rb, e0.y, cvb[1]);          \
        cvb[2] = fmaf(rb, e0.z, cvb[2]); cvb[3] = fmaf(rb, e0.w, cvb[3]);          \
        cvb[4] = fmaf(rb, e1.x, cvb[4]); cvb[5] = fmaf(rb, e1.y, cvb[5]);          \
        cvb[6] = fmaf(rb, e1.z, cvb[6]); cvb[7] = fmaf(rb, e1.w, cvb[7]);          \
    }                                                                              \
}

#pragma unroll
    for (int c = 0; c < 32; c += 2) {
        CHUNK(HA0, UA0, HB0, UB0, HA1, UA1, HB1, UB1, c)
        CHUNK(HA1, UA1, HB1, UB1, HA0, UA0, HB0, UB0, c + 1)
    }
#undef CHUNK

    // ---- wave reduce (butterfly) ----
#pragma unroll
    for (int off = 32; off > 0; off >>= 1) {
        s1a += __shfl_xor(s1a, off); s2a += __shfl_xor(s2a, off);
        s1b += __shfl_xor(s1b, off); s2b += __shfl_xor(s2b, off);
    }
#pragma unroll
    for (int d2 = 0; d2 < 8; ++d2)
#pragma unroll
        for (int off = 32; off > 0; off >>= 1) {
            cva[d2] += __shfl_xor(cva[d2], off);
            cvb[d2] += __shfl_xor(cvb[d2], off);
        }
#pragma unroll
    for (int off = 32; off > 0; off >>= 1) {
        const float ova = __shfl_xor(bra, off);
        const int oia = __shfl_xor(bia, off);
        if (ova > bra || (ova == bra && oia < bia)) { bra = ova; bia = oia; }
        const float ovb = __shfl_xor(brb, off);
        const int oib = __shfl_xor(bib, off);
        if (ovb > brb || (ovb == brb && oib < bib)) { brb = ovb; bib = oib; }
    }

    if (lane == 0) {
#pragma unroll
        for (int d2 = 0; d2 < 8; ++d2) {
            out[(size_t)n * 16 + g * 8 + d2] = cva[d2] / s1a;
            out[(size_t)(n + 1) * 16 + g * 8 + d2] = cvb[d2] / s1b;
        }
        out[65537 + (size_t)n * 2 + g] = (float)bia;
        out[65537 + (size_t)(n + 1) * 2 + g] = (float)bib;
        mrow[n * 2 + g] = mka ? (1.0f / s2a) : 0.f;
        mrow[(n + 1) * 2 + g] = mkb ? (1.0f / s2b) : 0.f;
    }
}

// ---------------- marginal accumulate: q = eh * (mask/S2), summed over rows ---
// float4 over v; 128-row segment per block; eh from L3; zero transcendentals.
__global__ __launch_bounds__(256) void marg_acc(const float* __restrict__ ehid,
                                                const float* __restrict__ mrow,
                                                float* __restrict__ part) {
    const int v4 = (blockIdx.x * 256 + threadIdx.x) * 4;
    const int seg = blockIdx.y;
    const int g = blockIdx.z;
    const float* hp = ehid + (size_t)g * Vsz + v4;
    const int nbeg = seg * (Mrows / NSEG);

    float4 a0 = {0.f, 0.f, 0.f, 0.f}, a1 = {0.f, 0.f, 0.f, 0.f};
    for (int nn = nbeg; nn < nbeg + Mrows / NSEG; nn += 2) {
        const float4 e0 = *(const float4*)(hp + (size_t)nn * Ncols);
        const float4 e1 = *(const float4*)(hp + (size_t)(nn + 1) * Ncols);
        const float w0 = mrow[nn * 2 + g];
        const float w1 = mrow[(nn + 1) * 2 + g];
        a0.x = fmaf(e0.x, w0, a0.x); a0.y = fmaf(e0.y, w0, a0.y);
        a0.z = fmaf(e0.z, w0, a0.z); a0.w = fmaf(e0.w, w0, a0.w);
        a1.x = fmaf(e1.x, w1, a1.x); a1.y = fmaf(e1.y, w1, a1.y);
        a1.z = fmaf(e1.z, w1, a1.z); a1.w = fmaf(e1.w, w1, a1.w);
    }
    float4 r;
    r.x = a0.x + a1.x; r.y = a0.y + a1.y; r.z = a0.z + a1.z; r.w = a0.w + a1.w;
    *(float4*)(part + ((size_t)seg * 2 + g) * Vsz + v4) = r;
}

// ---------------- marginal reduce over segments --------------------------------
__global__ __launch_bounds__(256) void reduce_marg(const float* __restrict__ part,
                                                   float* __restrict__ marginal) {
    const int g = blockIdx.y;
    const int v = blockIdx.x * 256 + threadIdx.x;
    float s = 0.f;
    for (int b = 0; b < NSEG; ++b) s += part[((size_t)b * 2 + g) * Vsz + v];
    marginal[g * Vsz + v] = s;
}

// ---------------- Perplexity --------------------------------------------------
__global__ __launch_bounds__(256) void ppl_kernel(const float* __restrict__ marginal,
                                                  const int* __restrict__ mask,
                                                  float* __restrict__ out) {
    const int tid = threadIdx.x;
    const int lane = tid & 63;
    const int wid = tid >> 6;
    __shared__ float red[4];
    __shared__ int redi[4];

    int ms = 0;
    for (int i = tid; i < Mrows; i += 256) ms += mask[i];
#pragma unroll
    for (int off = 32; off > 0; off >>= 1) ms += __shfl_down(ms, off);
    if (lane == 0) redi[wid] = ms;
    __syncthreads();
    const float inv = 1.0f / (float)(redi[0] + redi[1] + redi[2] + redi[3]);

    float ppl = 0.f;
    for (int g = 0; g < 2; ++g) {
        float part = 0.f;
        for (int v = tid; v < Vsz; v += 256) {
            const float m = marginal[g * Vsz + v] * inv;
            part += m * logf(m + 1e-7f);
        }
#pragma unroll
        for (int off = 32; off > 0; off >>= 1) part += __shfl_down(part, off);
        __syncthreads();
        if (lane == 0) red[wid] = part;
        __syncthreads();
        if (tid == 0) ppl += __expf(-(red[0] + red[1] + red[2] + red[3]));
        __syncthreads();
    }
    if (tid == 0) out[65536] = ppl;
}

// ---------------- Launch ------------------------------------------------------
extern "C" void kernel_launch(void* const* d_in, const int* in_sizes, int n_in,
                              void* d_out, int out_size, void* d_ws, size_t ws_size,
                              hipStream_t stream) {
    const float* x    = (const float*)d_in[0];
    const float* u    = (const float*)d_in[1];
    const float* emb  = (const float*)d_in[2];
    const float* w    = (const float*)d_in[3];
    const float* bias = (const float*)d_in[4];
    const int*   mask = (const int*)d_in[5];
    float* out = (float*)d_out;

    char* base = (char*)d_ws;
    float* marginal = (float*)base;                                    // 64 KB
    float* mrow = (float*)(base + 65536);                              // 32 KB
    float* part = (float*)(base + 131072);                             // 2 MB
    __hip_bfloat16* Ahi = (__hip_bfloat16*)(base + 2228224);           // 2 MB
    __hip_bfloat16* Alo = Ahi + 1048576;                               // 2 MB
    __hip_bfloat16* Bhi = Alo + 1048576;                               // 8 MB
    __hip_bfloat16* Blo = Bhi + 4194304;                               // 8 MB
    const size_t ehid_off = 2228224 + 4194304 + 16777216;              // ~23.2 MB
    float* ehid = (float*)(base + ehid_off);

    split_bf16<<<4096, 256, 0, stream>>>(x, Ahi, Alo);      // 1M elems
    split_bf16<<<16384, 256, 0, stream>>>(w, Bhi, Blo);     // 4M elems

    dim3 gg(Mrows / 128, Ncols / 128);
    gemm_mfma<<<gg, 256, 0, stream>>>(Ahi, Alo, Bhi, Blo, bias, ehid);
    dim3 pg(Mrows / 8, 2);
    phase2<<<pg, 256, 0, stream>>>(ehid, u, emb, mask, mrow, out);

    marg_acc<<<dim3(Vsz / 1024, NSEG, 2), 256, 0, stream>>>(ehid, mrow, part);
    reduce_marg<<<dim3(Vsz / 256, 2), 256, 0, stream>>>(part, marginal);
    ppl_kernel<<<1, 256, 0, stream>>>(marginal, mask, out);
}